// Round 2
// baseline (346.379 us; speedup 1.0000x reference)
//
#include <hip/hip_runtime.h>
#include <math.h>

// Problem constants
#define TT 9000          // samples per channel
#define DT 300           // crop length
#define KK 64            // crops per channel
#define NB 35            // band bins: rfft bins 7..41
#define KMIN 7
#define NCH 4096         // B*C channels
#define NPAIR (KK * NB)  // 2240 outputs per channel

// GEMM per channel: C[64 x 96] = A[64 x 320] * W[320 x 96]  (16x16x32 bf16 MFMA)
// v3: W lives in LDS (the compiler re-sank v2's "register-resident" W loads
// into the k-loop -> v1/v2 were global-load-latency-bound, MfmaUtil 4-7%).
//  - W staged via global_load_lds (async, linear both sides) in TWO 30 KB
//    halves (ks 0-4, then 5-9) so LDS stays at 72.3 KB -> 2 blocks/CU
//  - crops pre-gathered to bf16 rows [64][328] -> one aligned ds_read_b128
//    per A-fragment (bank-balanced: 8 lanes per 4-bank group)
//  - k-loop: 4x ds_read_b128 + 4 independent MFMAs, no globals, no barriers

typedef __bf16 bf16;
typedef __attribute__((ext_vector_type(8))) __bf16 bf16x8;
typedef __attribute__((ext_vector_type(4))) __bf16 bf16x4;
typedef __attribute__((ext_vector_type(4))) float f32x4;

#define NFRAG_ELEMS (10 * 6 * 64 * 8)   // 30720 bf16 = 61440 B in d_ws

// W table in B-fragment order: flat idx ((kstep*6 + nt)*64 + lane)*8 + j
// B-frag layout (16x16x32): lane l holds B[k = kstep*32 + (l>>4)*8 + j][n = l&15]
__global__ void build_w(bf16* __restrict__ tab) {
    int i = blockIdx.x * blockDim.x + threadIdx.x;
    if (i >= NFRAG_ELEMS) return;
    int j    = i & 7;
    int l    = (i >> 3) & 63;
    int f    = i >> 9;           // frag index = kstep*6 + nt
    int nt   = f % 6;
    int ks   = f / 6;
    int quad = l >> 4;
    int c    = l & 15;
    int k    = ks * 32 + quad * 8 + j;   // time index 0..319
    int jf   = (nt % 3) * 16 + c;        // band bin index 0..47
    float v = 0.0f;
    if (jf <= NB - 1 && k < DT) {
        int bin = jf + KMIN;                       // rfft bin 7..41
        int ph  = (bin * k) % DT;                  // exact integer phase
        float ang = 0.02094395102393195f * (float)ph;  // 2*pi/300 * ph
        v = (nt >= 3) ? sinf(ang) : cosf(ang);
    }
    tab[i] = (bf16)v;
}

#define ROWB  656    // bytes per crop row in LDS: 328 bf16 (320 data + pad), 41*16
#define WHALF 30720  // bytes per W half: 5 ks * 6 nt * 1024 B/frag

__global__ __launch_bounds__(384, 3) void st_mfma(
        const float* __restrict__ input,    // [NCH, TT] fp32
        const int*   __restrict__ offsets,  // [NCH, KK] int32
        const bf16*  __restrict__ tab,      // W in B-frag order
        float*       __restrict__ out) {    // [NCH, KK, NB] fp32
    __shared__ __align__(16) unsigned char cb[KK * ROWB];   // 41984 B bf16 crops
    __shared__ __align__(16) unsigned char wbuf[WHALF];     // 30720 B W half
    __shared__ __align__(16) float part[KK][4];             // band partials [crop][pg]
    __shared__ int offs[KK];

    const int bc   = blockIdx.x;
    const int tid  = threadIdx.x;
    const int wid  = tid >> 6;
    const int lane = tid & 63;

    if (tid < KK) offs[tid] = offsets[bc * KK + tid];
    __syncthreads();

    const unsigned char* wsrc = (const unsigned char*)tab;

    // ---- async-stage W half 0 (ks 0..4) into LDS: 30 chunks of 1024 B ----
    // Linear in global AND in LDS -> global_load_lds applies (wave-uniform dest
    // + lane*16, per-lane source). Latency hides under the gather below.
#pragma unroll
    for (int i = 0; i < 5; ++i) {
        int chunk = wid * 5 + i;
        __builtin_amdgcn_global_load_lds(
            (const __attribute__((address_space(1))) void*)(wsrc + chunk * 1024 + lane * 16),
            (__attribute__((address_space(3))) void*)(wbuf + chunk * 1024),
            16, 0, 0);
    }

    // ---- gather crops -> bf16 rows in LDS ----
    // 64 crops * 80 chunks(16B) = 5120; p>=75 is the zero pad (k 300..319,
    // W rows there are zero, but LDS poison*0 must not produce NaN -> zero it).
    // Consecutive threads read consecutive 16B chunks -> coalesced runs ~1.2KB.
    const float* chan = input + (size_t)bc * TT;
#pragma unroll
    for (int i = 0; i < 14; ++i) {
        int n = tid + i * 384;
        if (n < KK * 80) {
            int r = n / 80;            // crop
            int p = n - r * 80;        // 16B chunk within crop
            float f0 = 0.f, f1 = 0.f, f2 = 0.f, f3 = 0.f;
            if (p < 75) {              // off+299 <= 8999: always in bounds
                const float* gp = chan + offs[r] + p * 4;
                f0 = gp[0]; f1 = gp[1]; f2 = gp[2]; f3 = gp[3];
            }
            bf16x4 v;
            v[0] = (bf16)f0; v[1] = (bf16)f1; v[2] = (bf16)f2; v[3] = (bf16)f3;
            *(bf16x4*)(cb + r * ROWB + p * 8) = v;   // 8B-aligned ds_write_b64
        }
    }
    __syncthreads();   // drains vmcnt(0)+lgkmcnt(0): gather + W half0 all visible

    const int mg   = wid & 1;    // M-group: crops mg*32 .. mg*32+31
    const int pg   = wid >> 1;   // bin group: bins pg*16 + c; cos nt=pg, sin nt=pg+3
    const int quad = lane >> 4;
    const int c    = lane & 15;

    // A-frag: lane holds A[m = c][k = ks*32 + quad*8 + j] -> one b128 per (M,ks).
    // Bank math: dword bank = 4*(c+quad) mod 32 -> 8 lanes per 4-bank group,
    // 1024 B spread evenly over 32 banks = structural minimum.
    const unsigned char* a0p = cb + (mg * 32 + c) * ROWB + quad * 16;
    const unsigned char* a1p = a0p + 16 * ROWB;

    f32x4 acc_c0 = {0.f,0.f,0.f,0.f}, acc_s0 = {0.f,0.f,0.f,0.f};
    f32x4 acc_c1 = {0.f,0.f,0.f,0.f}, acc_s1 = {0.f,0.f,0.f,0.f};

    // ---- k-loop half 0: ks = 0..4, pure LDS + MFMA ----
#pragma unroll
    for (int l = 0; l < 5; ++l) {
        bf16x8 a0 = *(const bf16x8*)(a0p + l * 64);
        bf16x8 a1 = *(const bf16x8*)(a1p + l * 64);
        bf16x8 wc = *(const bf16x8*)(wbuf + ((l * 6 + pg    ) * 64 + lane) * 16);
        bf16x8 wsn= *(const bf16x8*)(wbuf + ((l * 6 + pg + 3) * 64 + lane) * 16);
        acc_c0 = __builtin_amdgcn_mfma_f32_16x16x32_bf16(a0, wc,  acc_c0, 0, 0, 0);
        acc_s0 = __builtin_amdgcn_mfma_f32_16x16x32_bf16(a0, wsn, acc_s0, 0, 0, 0);
        acc_c1 = __builtin_amdgcn_mfma_f32_16x16x32_bf16(a1, wc,  acc_c1, 0, 0, 0);
        acc_s1 = __builtin_amdgcn_mfma_f32_16x16x32_bf16(a1, wsn, acc_s1, 0, 0, 0);
    }

    __syncthreads();   // all waves done reading half 0

    // ---- async-stage W half 1 (ks 5..9) ----
#pragma unroll
    for (int i = 0; i < 5; ++i) {
        int chunk = wid * 5 + i;
        __builtin_amdgcn_global_load_lds(
            (const __attribute__((address_space(1))) void*)(wsrc + WHALF + chunk * 1024 + lane * 16),
            (__attribute__((address_space(3))) void*)(wbuf + chunk * 1024),
            16, 0, 0);
    }
    __syncthreads();   // drains vmcnt(0): half 1 visible (stall covered by co-resident block)

    // ---- k-loop half 1: ks = 5..9 ----
#pragma unroll
    for (int l = 0; l < 5; ++l) {
        bf16x8 a0 = *(const bf16x8*)(a0p + (5 + l) * 64);
        bf16x8 a1 = *(const bf16x8*)(a1p + (5 + l) * 64);
        bf16x8 wc = *(const bf16x8*)(wbuf + ((l * 6 + pg    ) * 64 + lane) * 16);
        bf16x8 wsn= *(const bf16x8*)(wbuf + ((l * 6 + pg + 3) * 64 + lane) * 16);
        acc_c0 = __builtin_amdgcn_mfma_f32_16x16x32_bf16(a0, wc,  acc_c0, 0, 0, 0);
        acc_s0 = __builtin_amdgcn_mfma_f32_16x16x32_bf16(a0, wsn, acc_s0, 0, 0, 0);
        acc_c1 = __builtin_amdgcn_mfma_f32_16x16x32_bf16(a1, wc,  acc_c1, 0, 0, 0);
        acc_s1 = __builtin_amdgcn_mfma_f32_16x16x32_bf16(a1, wsn, acc_s1, 0, 0, 0);
    }

    // ---- epilogue: power, per-wave band partials, cross-wave sum, store ----
    // C/D layout: col = lane&15 (bin pg*16+c), row = quad*4 + r (crop in tile).
    // Invalid bins (pg==2, c>2) have zero W cols -> p==0, harmless in the sum.
    float pv[2][4];
#pragma unroll
    for (int m = 0; m < 2; ++m) {
#pragma unroll
        for (int r = 0; r < 4; ++r) {
            float cv = m ? acc_c1[r] : acc_c0[r];
            float sv = m ? acc_s1[r] : acc_s0[r];
            float p  = cv * cv + sv * sv;
            pv[m][r] = p;
            float s = p;
#pragma unroll
            for (int d = 1; d < 16; d <<= 1) s += __shfl_xor(s, d, 64);  // in-quad
            if (c == 0) part[mg * 32 + m * 16 + quad * 4 + r][pg] = s;
        }
    }
    __syncthreads();

    float* ob = out + (size_t)bc * NPAIR;
#pragma unroll
    for (int m = 0; m < 2; ++m) {
#pragma unroll
        for (int r = 0; r < 4; ++r) {
            int crop = mg * 32 + m * 16 + quad * 4 + r;
            f32x4 t = *(const f32x4*)part[crop];        // b128 broadcast read
            float rinv = __builtin_amdgcn_rcpf(t[0] + t[1] + t[2]);
            if (pg < 2 || c < 3)
                ob[crop * 35 + pg * 16 + c] = pv[m][r] * rinv;
        }
    }
}

extern "C" void kernel_launch(void* const* d_in, const int* in_sizes, int n_in,
                              void* d_out, int out_size, void* d_ws, size_t ws_size,
                              hipStream_t stream) {
    const float* input   = (const float*)d_in[0];  // [256,16,9000] fp32
    const int*   offsets = (const int*)d_in[1];    // [256,16,64] int32
    float*       out     = (float*)d_out;          // [256,16,64,35] fp32
    bf16*        tab     = (bf16*)d_ws;            // 61440 B

    // d_ws is re-poisoned before every timed launch -> rebuild table each call.
    build_w<<<(NFRAG_ELEMS + 255) / 256, 256, 0, stream>>>(tab);
    st_mfma<<<NCH, 384, 0, stream>>>(input, offsets, tab, out);
}

// Round 3
// 251.153 us; speedup vs baseline: 1.3792x; 1.3792x over previous
//
#include <hip/hip_runtime.h>
#include <math.h>

// Problem constants
#define TT 9000          // samples per channel
#define DT 300           // crop length
#define KK 64            // crops per channel
#define NB 35            // band bins: rfft bins 7..41
#define KMIN 7
#define NCH 4096         // B*C channels
#define NPAIR (KK * NB)  // 2240 outputs per channel

// GEMM per channel: C[64 x 96] = A[64 x 320] * W[320 x 96]  (16x16x32 bf16 MFMA)
// v4 = v1 structure (best: 87us @ 40% occ) with the LDS footprint halved.
// Finding: dur x occupancy ~= const across v1/v2/v3 -> latency-bound, throughput
// proportional to resident waves. v1's only capacity cost is the fp32 channel
// (36 KB -> 4 blocks/CU). Store channel as bf16 (18 KB) -> 8 blocks/CU
// (32 waves/CU). Random crop offsets give only 2B alignment in a bf16 buffer;
// fix branchlessly: read 5 dwords at s>>1 (ds_read2_b32 pairs) + 4x
// v_alignbit_b32 with per-lane shift (off&1)<<4. No cvt in the k-loop.
// W keeps streaming from the L2-resident 61 KB table (per-wave, like v1).

typedef __bf16 bf16;
typedef __attribute__((ext_vector_type(8))) __bf16 bf16x8;
typedef __attribute__((ext_vector_type(4))) __bf16 bf16x4;
typedef __attribute__((ext_vector_type(4))) float f32x4;

#define NFRAG_ELEMS (10 * 6 * 64 * 8)   // 30720 bf16 = 61440 B in d_ws

// W table in B-fragment order: flat idx ((kstep*6 + nt)*64 + lane)*8 + j
// B-frag layout (16x16x32): lane l holds B[k = kstep*32 + (l>>4)*8 + j][n = l&15]
__global__ void build_w(bf16* __restrict__ tab) {
    int i = blockIdx.x * blockDim.x + threadIdx.x;
    if (i >= NFRAG_ELEMS) return;
    int j    = i & 7;
    int l    = (i >> 3) & 63;
    int f    = i >> 9;           // frag index = kstep*6 + nt
    int nt   = f % 6;
    int ks   = f / 6;
    int quad = l >> 4;
    int c    = l & 15;
    int k    = ks * 32 + quad * 8 + j;   // time index 0..319
    int jf   = (nt % 3) * 16 + c;        // band bin index 0..47
    float v = 0.0f;
    if (jf <= NB - 1 && k < DT) {
        int bin = jf + KMIN;                       // rfft bin 7..41
        int ph  = (bin * k) % DT;                  // exact integer phase
        float ang = 0.02094395102393195f * (float)ph;  // 2*pi/300 * ph
        v = (nt >= 3) ? sinf(ang) : cosf(ang);
    }
    tab[i] = (bf16)v;
}

#define SPAD 9024   // samples incl. zeroed tail pad (reads reach sample 9021)

__global__ __launch_bounds__(256, 8) void st_mfma(
        const float* __restrict__ input,    // [NCH, TT] fp32
        const int*   __restrict__ offsets,  // [NCH, KK] int32
        const bf16*  __restrict__ tab,      // W in B-frag order
        float*       __restrict__ out) {    // [NCH, KK, NB] fp32
    __shared__ __align__(16) bf16 sig[SPAD];   // 18048 B bf16 channel
    __shared__ int offs[KK];

    const int bc  = blockIdx.x;
    const int tid = threadIdx.x;

    // ---- stage channel -> bf16 LDS (coalesced float4 reads, b64 writes) ----
    const float4* src = (const float4*)(input + (size_t)bc * TT);
#pragma unroll
    for (int i = 0; i < 9; ++i) {        // 9*256 = 2304 >= 2250 float4 chunks
        int idx = tid + i * 256;
        if (idx < TT / 4) {
            float4 v = src[idx];
            bf16x4 b;
            b[0] = (bf16)v.x; b[1] = (bf16)v.y; b[2] = (bf16)v.z; b[3] = (bf16)v.w;
            *(bf16x4*)(sig + idx * 4) = b;   // byte 8*idx: 8B-aligned
        }
    }
    if (tid < SPAD - TT) sig[TT + tid] = (bf16)0.0f;  // zero pad (poison*0 != NaN)
    if (tid < KK) offs[tid] = offsets[bc * KK + tid];
    __syncthreads();

    const int w    = tid >> 6;    // wave = M-tile (16 crops)
    const int lane = tid & 63;
    const int quad = lane >> 4;
    const int c    = lane & 15;

    // A-frag: lane holds A[m = c][k = ks*32 + quad*8 + j], j=0..7.
    // Samples [s, s+8), s = off + ks*32 + quad*8. Parity of s == parity of off
    // (constant across ks/quad) -> one per-lane realign shift for the kernel.
    const int off = offs[w * 16 + c];
    const int d0  = (off + quad * 8) >> 1;          // dword index of s (floor)
    const unsigned sh = (unsigned)((off & 1) << 4); // 0 or 16
    const int* ip = (const int*)sig;

    const bf16x8* wt = (const bf16x8*)tab;

    f32x4 acc[6];
#pragma unroll
    for (int nt = 0; nt < 6; ++nt) acc[nt] = (f32x4){0.f, 0.f, 0.f, 0.f};

#pragma unroll
    for (int ks = 0; ks < 10; ++ks) {
        // build A fragment: 5 dword LDS reads + 4 alignbit (branchless realign)
        const int db = d0 + ks * 16;
        int dw0 = ip[db + 0], dw1 = ip[db + 1], dw2 = ip[db + 2],
            dw3 = ip[db + 3], dw4 = ip[db + 4];
        union { unsigned u[4]; bf16x8 v; } a;
        a.u[0] = __builtin_amdgcn_alignbit((unsigned)dw1, (unsigned)dw0, sh);
        a.u[1] = __builtin_amdgcn_alignbit((unsigned)dw2, (unsigned)dw1, sh);
        a.u[2] = __builtin_amdgcn_alignbit((unsigned)dw3, (unsigned)dw2, sh);
        a.u[3] = __builtin_amdgcn_alignbit((unsigned)dw4, (unsigned)dw3, sh);

#pragma unroll
        for (int nt = 0; nt < 6; ++nt)
            acc[nt] = __builtin_amdgcn_mfma_f32_16x16x32_bf16(
                a.v, wt[(ks * 6 + nt) * 64 + lane], acc[nt], 0, 0, 0);
    }

    // Epilogue, all in registers. C/D layout: col = lane&15, row = quad*4 + r.
    // cos_j in acc[i], sin_j in acc[i+3] (same lane), j = i*16 + c.
    float* o = out + (size_t)bc * NPAIR;
#pragma unroll
    for (int r = 0; r < 4; ++r) {
        float p0 = acc[0][r] * acc[0][r] + acc[3][r] * acc[3][r];  // j = c
        float p1 = acc[1][r] * acc[1][r] + acc[4][r] * acc[4][r];  // j = 16+c
        float p2 = acc[2][r] * acc[2][r] + acc[5][r] * acc[5][r];  // j = 32+c (c<=2)
        float s = p0 + p1 + ((c <= 2) ? p2 : 0.0f);
        // band sum: reduce across the 16 lanes of this quad (xor masks stay in-quad)
#pragma unroll
        for (int d = 1; d < 16; d <<= 1) s += __shfl_xor(s, d, 64);
        float rinv = 1.0f / s;
        int crop = w * 16 + quad * 4 + r;
        float* oc = o + crop * NB;
        oc[c] = p0 * rinv;
        oc[16 + c] = p1 * rinv;
        if (c <= 2) oc[32 + c] = p2 * rinv;
    }
}

extern "C" void kernel_launch(void* const* d_in, const int* in_sizes, int n_in,
                              void* d_out, int out_size, void* d_ws, size_t ws_size,
                              hipStream_t stream) {
    const float* input   = (const float*)d_in[0];  // [256,16,9000] fp32
    const int*   offsets = (const int*)d_in[1];    // [256,16,64] int32
    float*       out     = (float*)d_out;          // [256,16,64,35] fp32
    bf16*        tab     = (bf16*)d_ws;            // 61440 B

    // d_ws is re-poisoned before every timed launch -> rebuild table each call.
    build_w<<<(NFRAG_ELEMS + 255) / 256, 256, 0, stream>>>(tab);
    st_mfma<<<NCH, 256, 0, stream>>>(input, offsets, tab, out);
}

// Round 4
// 233.190 us; speedup vs baseline: 1.4854x; 1.0770x over previous
//
#include <hip/hip_runtime.h>
#include <math.h>

// Problem constants
#define TT 9000          // samples per channel
#define DT 300           // crop length
#define KK 64            // crops per channel
#define NB 35            // band bins: rfft bins 7..41
#define KMIN 7
#define NCH 4096         // B*C channels
#define NPAIR (KK * NB)  // 2240 outputs per channel

// GEMM per channel: C[64 x 96] = A[64 x 320] * W[320 x 96]  (16x16x32 bf16 MFMA)
// v5 = v3's k-loop (W resident in LDS: best per-wave efficiency, dur*occ=32)
//    + v4's LDS budget (bf16 channel, 18 KB: occupancy lever).
// Evidence: v4 (W streamed from global, VGPR 28) serialized every W load
// against its MFMA -> per-wave efficiency 2.3x worse than v3 despite 85% occ.
// Here: full 60 KB W staged ONCE per block via global_load_lds (single phase),
// k-loop is pure {ds_read + MFMA}, no globals, no barriers.
// LDS ~80.5 KB -> 2 blocks/CU; 12 waves/block -> 24 waves/CU (75% cap).
// Wave (m 0..3, pg 0..2): M-tile m, bin pair (cos nt=pg, sin nt=pg+3).
// Band unit-sum crosses the 3 pg-waves via a tiny part[] buffer + 1 barrier.

typedef __bf16 bf16;
typedef __attribute__((ext_vector_type(8))) __bf16 bf16x8;
typedef __attribute__((ext_vector_type(4))) __bf16 bf16x4;
typedef __attribute__((ext_vector_type(4))) float f32x4;

#define NFRAG_ELEMS (10 * 6 * 64 * 8)   // 30720 bf16 = 61440 B in d_ws
#define WBYTES 61440

// W table in B-fragment order: flat idx ((kstep*6 + nt)*64 + lane)*8 + j
// B-frag layout (16x16x32): lane l holds B[k = kstep*32 + (l>>4)*8 + j][n = l&15]
__global__ void build_w(bf16* __restrict__ tab) {
    int i = blockIdx.x * blockDim.x + threadIdx.x;
    if (i >= NFRAG_ELEMS) return;
    int j    = i & 7;
    int l    = (i >> 3) & 63;
    int f    = i >> 9;           // frag index = kstep*6 + nt
    int nt   = f % 6;
    int ks   = f / 6;
    int quad = l >> 4;
    int c    = l & 15;
    int k    = ks * 32 + quad * 8 + j;   // time index 0..319
    int jf   = (nt % 3) * 16 + c;        // band bin index 0..47
    float v = 0.0f;
    if (jf <= NB - 1 && k < DT) {
        int bin = jf + KMIN;                       // rfft bin 7..41
        int ph  = (bin * k) % DT;                  // exact integer phase
        float ang = 0.02094395102393195f * (float)ph;  // 2*pi/300 * ph
        v = (nt >= 3) ? sinf(ang) : cosf(ang);
    }
    tab[i] = (bf16)v;
}

#define SPAD 9024   // bf16 samples incl. zeroed tail (alignbit reads reach 9021)

__global__ __launch_bounds__(768, 6) void st_mfma(
        const float* __restrict__ input,    // [NCH, TT] fp32
        const int*   __restrict__ offsets,  // [NCH, KK] int32
        const bf16*  __restrict__ tab,      // W in B-frag order
        float*       __restrict__ out) {    // [NCH, KK, NB] fp32
    __shared__ __align__(16) bf16 sig[SPAD];                 // 18048 B channel
    __shared__ __align__(16) unsigned char wlds[WBYTES];     // 61440 B W table
    __shared__ __align__(16) float part[KK][3];              // 768 B band partials
    __shared__ int offs[KK];                                 // 256 B

    const int bc   = blockIdx.x;
    const int tid  = threadIdx.x;
    const int wid  = tid >> 6;   // 0..11
    const int lane = tid & 63;

    // ---- async-stage full W table: 60 chunks x 1024 B, 5 per wave ----
    // Linear in global AND LDS (wave-uniform dest + lane*16) -> global_load_lds.
    // Latency hides under the channel gather below; barrier drains vmcnt.
#pragma unroll
    for (int i = 0; i < 5; ++i) {
        int chunk = wid * 5 + i;
        __builtin_amdgcn_global_load_lds(
            (const __attribute__((address_space(1))) void*)((const unsigned char*)tab + chunk * 1024 + lane * 16),
            (__attribute__((address_space(3))) void*)(wlds + chunk * 1024),
            16, 0, 0);
    }

    // ---- stage channel -> bf16 LDS (coalesced float4 reads, b64 writes) ----
    const float4* src = (const float4*)(input + (size_t)bc * TT);
#pragma unroll
    for (int i = 0; i < 3; ++i) {        // 3*768 = 2304 >= 2250 float4 chunks
        int idx = tid + i * 768;
        if (idx < TT / 4) {
            float4 v = src[idx];
            bf16x4 b;
            b[0] = (bf16)v.x; b[1] = (bf16)v.y; b[2] = (bf16)v.z; b[3] = (bf16)v.w;
            *(bf16x4*)(sig + idx * 4) = b;   // byte 8*idx: 8B-aligned
        }
    }
    if (tid < SPAD - TT) sig[TT + tid] = (bf16)0.0f;  // zero pad (poison*0 != NaN)
    if (tid < KK) offs[tid] = offsets[bc * KK + tid];
    __syncthreads();   // drains vmcnt (W stage) + lgkmcnt (sig writes)

    const int m    = wid & 3;    // M-tile: crops m*16 .. m*16+15
    const int pg   = wid >> 2;   // bin group: bins pg*16 + c; cos nt=pg, sin nt=pg+3
    const int quad = lane >> 4;
    const int c    = lane & 15;

    // A-frag: lane holds A[row = c][k = ks*32 + quad*8 + j], j=0..7.
    // Samples [s, s+8), s = off + ks*32 + quad*8; parity of s == parity of off
    // -> one per-lane alignbit shift for the whole kernel (branchless realign).
    const int off = offs[m * 16 + c];
    const int d0  = (off + quad * 8) >> 1;          // dword index (floor)
    const unsigned sh = (unsigned)((off & 1) << 4); // 0 or 16
    const int* ip = (const int*)sig;

    // W frags for this wave: nt=pg (cos) and nt=pg+3 (sin), stride-16 b128
    // reads (structural-minimum banking, conflict-free).
    const unsigned char* wp = wlds + (size_t)(pg * 64 + lane) * 16;

    f32x4 acc_c = {0.f,0.f,0.f,0.f}, acc_s = {0.f,0.f,0.f,0.f};

#pragma unroll
    for (int ks = 0; ks < 10; ++ks) {
        // A fragment: 5 dword LDS reads (ds_read2_b32 pairs) + 4 alignbit
        const int db = d0 + ks * 16;
        int dw0 = ip[db + 0], dw1 = ip[db + 1], dw2 = ip[db + 2],
            dw3 = ip[db + 3], dw4 = ip[db + 4];
        union { unsigned u[4]; bf16x8 v; } a;
        a.u[0] = __builtin_amdgcn_alignbit((unsigned)dw1, (unsigned)dw0, sh);
        a.u[1] = __builtin_amdgcn_alignbit((unsigned)dw2, (unsigned)dw1, sh);
        a.u[2] = __builtin_amdgcn_alignbit((unsigned)dw3, (unsigned)dw2, sh);
        a.u[3] = __builtin_amdgcn_alignbit((unsigned)dw4, (unsigned)dw3, sh);

        bf16x8 wc = *(const bf16x8*)(wp + (ks * 6    ) * 1024);
        bf16x8 wn = *(const bf16x8*)(wp + (ks * 6 + 3) * 1024);
        acc_c = __builtin_amdgcn_mfma_f32_16x16x32_bf16(a.v, wc, acc_c, 0, 0, 0);
        acc_s = __builtin_amdgcn_mfma_f32_16x16x32_bf16(a.v, wn, acc_s, 0, 0, 0);
    }

    // ---- epilogue ----
    // C/D layout: col = lane&15 (bin pg*16+c), row = quad*4 + r (crop in tile).
    // Invalid bins (pg==2, c>2) have zero W cols -> p==0, harmless in sums.
    float pv[4];
#pragma unroll
    for (int r = 0; r < 4; ++r) {
        float p = acc_c[r] * acc_c[r] + acc_s[r] * acc_s[r];
        pv[r] = p;
        float s = p;
#pragma unroll
        for (int d = 1; d < 16; d <<= 1) s += __shfl_xor(s, d, 64);  // in-quad
        if (c == 0) part[m * 16 + quad * 4 + r][pg] = s;
    }
    __syncthreads();

    float* ob = out + (size_t)bc * NPAIR;
#pragma unroll
    for (int r = 0; r < 4; ++r) {
        int crop = m * 16 + quad * 4 + r;
        float s = part[crop][0] + part[crop][1] + part[crop][2];
        float rinv = __builtin_amdgcn_rcpf(s);
        if (pg < 2 || c < 3)
            ob[crop * NB + pg * 16 + c] = pv[r] * rinv;
    }
}

extern "C" void kernel_launch(void* const* d_in, const int* in_sizes, int n_in,
                              void* d_out, int out_size, void* d_ws, size_t ws_size,
                              hipStream_t stream) {
    const float* input   = (const float*)d_in[0];  // [256,16,9000] fp32
    const int*   offsets = (const int*)d_in[1];    // [256,16,64] int32
    float*       out     = (float*)d_out;          // [256,16,64,35] fp32
    bf16*        tab     = (bf16*)d_ws;            // 61440 B

    // d_ws is re-poisoned before every timed launch -> rebuild table each call.
    build_w<<<(NFRAG_ELEMS + 255) / 256, 256, 0, stream>>>(tab);
    st_mfma<<<NCH, 768, 0, stream>>>(input, offsets, tab, out);
}